// Round 1
// baseline (1346.308 us; speedup 1.0000x reference)
//
#include <hip/hip_runtime.h>
#include <hip/hip_bf16.h>
#include <stdint.h>

#define S0N 663552
#define S1N 73728
#define S2N 8192

typedef __attribute__((ext_vector_type(8))) short bf16x8;
typedef __attribute__((ext_vector_type(4))) float floatx4;

static constexpr int LDK = 72;   // 64 + 8 bf16 pad (16B) -> breaks 128B bank stride, keeps b128 alignment

__device__ __forceinline__ unsigned short f2b(float f) {
    union { float f; unsigned u; } v; v.f = f;
    unsigned r = v.u + 0x7fffu + ((v.u >> 16) & 1u);   // RNE to bf16
    return (unsigned short)(r >> 16);
}
__device__ __forceinline__ float b2f(unsigned short h) {
    union { unsigned u; float f; } v; v.u = ((unsigned)h) << 16;
    return v.f;
}

// stage 128 rows x 64 cols of fp32 -> bf16 into LDS [128][LDK]
__device__ __forceinline__ void stage_f32(const float* __restrict__ g, int rowStride,
                                          unsigned short* lds, int tid) {
    int r = tid >> 4;                 // 16 threads per row, float4 each -> 64 cols
    const int c = (tid & 15) << 2;
    #pragma unroll
    for (int it = 0; it < 8; ++it, r += 16) {
        const float4 v = *(const float4*)(g + (size_t)r * rowStride + c);
        unsigned short* d = &lds[r * LDK + c];
        d[0] = f2b(v.x); d[1] = f2b(v.y); d[2] = f2b(v.z); d[3] = f2b(v.w);
    }
}

// stage 128 rows x 64 cols of bf16 -> LDS [128][LDK]
__device__ __forceinline__ void stage_b16(const unsigned short* __restrict__ g, int rowStride,
                                          unsigned short* lds, int tid) {
    int r = tid >> 3;                 // 8 threads per row, 16B each -> 64 cols
    const int c = (tid & 7) << 3;
    #pragma unroll
    for (int it = 0; it < 4; ++it, r += 32) {
        const uint4 v = *(const uint4*)(g + (size_t)r * rowStride + c);
        *(uint4*)&lds[r * LDK + c] = v;
    }
}

// 128x128 tile, one BK=64 chunk: 4 waves, wave w owns rows [w*32, w*32+32)
__device__ __forceinline__ void mfma_128x128(const unsigned short* __restrict__ As,
                                             const unsigned short* __restrict__ Bs,
                                             floatx4 (&acc)[2][8],
                                             int wave, int l15, int quad) {
    #pragma unroll
    for (int kc = 0; kc < 64; kc += 32) {
        bf16x8 a[2], b[8];
        #pragma unroll
        for (int mt = 0; mt < 2; ++mt)
            a[mt] = *(const bf16x8*)&As[(wave * 32 + mt * 16 + l15) * LDK + kc + quad * 8];
        #pragma unroll
        for (int nt = 0; nt < 8; ++nt)
            b[nt] = *(const bf16x8*)&Bs[(nt * 16 + l15) * LDK + kc + quad * 8];
        #pragma unroll
        for (int mt = 0; mt < 2; ++mt)
            #pragma unroll
            for (int nt = 0; nt < 8; ++nt)
                acc[mt][nt] = __builtin_amdgcn_mfma_f32_16x16x32_bf16(a[mt], b[nt], acc[mt][nt], 0, 0, 0);
    }
}

// h0[i] = node_emb[parent0[i]+1] + leaky(content0[i] @ Wp^T + bp), stored bf16
__global__ __launch_bounds__(256, 2) void k_h0(
    const float* __restrict__ content, const float* __restrict__ Wp,
    const float* __restrict__ bp, const float* __restrict__ node_emb,
    const int* __restrict__ parent0, unsigned short* __restrict__ h0)
{
    __shared__ unsigned short As[128 * LDK];
    __shared__ unsigned short Bs[128 * LDK];
    const int tid = threadIdx.x;
    const int wave = tid >> 6, lane = tid & 63;
    const int l15 = lane & 15, quad = lane >> 4;
    const int row0 = blockIdx.x * 128;

    floatx4 acc[2][8];
    #pragma unroll
    for (int i = 0; i < 2; ++i)
        #pragma unroll
        for (int j = 0; j < 8; ++j) acc[i][j] = (floatx4)0.f;

    for (int k0 = 0; k0 < 256; k0 += 64) {
        stage_f32(content + (size_t)row0 * 256 + k0, 256, As, tid);
        stage_f32(Wp + k0, 256, Bs, tid);
        __syncthreads();
        mfma_128x128(As, Bs, acc, wave, l15, quad);
        __syncthreads();
    }

    // epilogue: + bp, leaky(0.1), + node_emb gather, -> bf16
    #pragma unroll
    for (int mt = 0; mt < 2; ++mt) {
        #pragma unroll
        for (int r = 0; r < 4; ++r) {
            const int grow = row0 + wave * 32 + mt * 16 + quad * 4 + r;
            const int p = parent0[grow] + 1;
            const float* ne = node_emb + (size_t)p * 128;
            unsigned short* orow = h0 + (size_t)grow * 128;
            #pragma unroll
            for (int nt = 0; nt < 8; ++nt) {
                const int col = nt * 16 + l15;
                float v = acc[mt][nt][r] + bp[col];
                v = v > 0.f ? v : 0.1f * v;
                v += ne[col];
                orow[col] = f2b(v);
            }
        }
    }
}

// out[d] = ( sum_{j<8} hsrc[src[randOff + d*8+j]]  (+ hself[d] - hsub[d]) ) / 8
// one wave per dst row; lane handles a bf16 pair (4B) -> 256B coalesced row accesses
__global__ __launch_bounds__(256, 4) void k_gather(
    const unsigned short* __restrict__ hsrc, const int* __restrict__ srcIdx,
    int randOff, const unsigned short* __restrict__ hself,
    const unsigned short* __restrict__ hsub, unsigned short* __restrict__ out)
{
    const int wave = threadIdx.x >> 6, lane = threadIdx.x & 63;
    const int d = blockIdx.x * 4 + wave;
    const int c2 = lane * 2;
    int idx[8];
    #pragma unroll
    for (int j = 0; j < 8; ++j) idx[j] = srcIdx[randOff + d * 8 + j];
    unsigned v[8];
    #pragma unroll
    for (int j = 0; j < 8; ++j)
        v[j] = *(const unsigned*)(hsrc + (size_t)idx[j] * 128 + c2);
    float ax = 0.f, ay = 0.f;
    #pragma unroll
    for (int j = 0; j < 8; ++j) {
        ax += b2f((unsigned short)(v[j] & 0xffffu));
        ay += b2f((unsigned short)(v[j] >> 16));
    }
    if (hself) {   // conv1: + h1[d] - h0[d]
        const unsigned s = *(const unsigned*)(hself + (size_t)d * 128 + c2);
        const unsigned u = *(const unsigned*)(hsub + (size_t)d * 128 + c2);
        ax += b2f((unsigned short)(s & 0xffffu)) - b2f((unsigned short)(u & 0xffffu));
        ay += b2f((unsigned short)(s >> 16))     - b2f((unsigned short)(u >> 16));
    }
    ax *= 0.125f; ay *= 0.125f;
    *(unsigned*)(out + (size_t)d * 128 + c2) =
        (unsigned)f2b(ax) | ((unsigned)f2b(ay) << 16);
}

// h = act(A1@W[:,0:128]^T + A2@W[:,128:256]^T + b) + act(A2@Wagg^T + bagg)
// !LAST: act=leaky, then row-L2-normalize, store bf16.  LAST: no act, store fp32.
template<bool LAST>
__global__ __launch_bounds__(256, 2) void k_combine(
    const unsigned short* __restrict__ A1, const unsigned short* __restrict__ A2,
    const float* __restrict__ W, const float* __restrict__ b,
    const float* __restrict__ Wagg, const float* __restrict__ bagg,
    unsigned short* __restrict__ outB, float* __restrict__ outF)
{
    __shared__ unsigned short As[128 * LDK];
    __shared__ unsigned short Bs[128 * LDK];
    __shared__ unsigned short Bs2[128 * LDK];
    const int tid = threadIdx.x;
    const int wave = tid >> 6, lane = tid & 63;
    const int l15 = lane & 15, quad = lane >> 4;
    const int row0 = blockIdx.x * 128;

    floatx4 acc1[2][8], acc2[2][8];
    #pragma unroll
    for (int i = 0; i < 2; ++i)
        #pragma unroll
        for (int j = 0; j < 8; ++j) { acc1[i][j] = (floatx4)0.f; acc2[i][j] = (floatx4)0.f; }

    // phase 1: A1 (h_dst) x W[:, 0:128]
    for (int k0 = 0; k0 < 128; k0 += 64) {
        stage_b16(A1 + (size_t)row0 * 128 + k0, 128, As, tid);
        stage_f32(W + k0, 256, Bs, tid);
        __syncthreads();
        mfma_128x128(As, Bs, acc1, wave, l15, quad);
        __syncthreads();
    }
    // phase 2: A2 (h_agg) x W[:, 128:256]  and  A2 x Wagg
    for (int k0 = 0; k0 < 128; k0 += 64) {
        stage_b16(A2 + (size_t)row0 * 128 + k0, 128, As, tid);
        stage_f32(W + 128 + k0, 256, Bs, tid);
        stage_f32(Wagg + k0, 128, Bs2, tid);
        __syncthreads();
        mfma_128x128(As, Bs,  acc1, wave, l15, quad);
        mfma_128x128(As, Bs2, acc2, wave, l15, quad);
        __syncthreads();
    }

    #pragma unroll
    for (int mt = 0; mt < 2; ++mt) {
        #pragma unroll
        for (int r = 0; r < 4; ++r) {
            const int grow = row0 + wave * 32 + mt * 16 + quad * 4 + r;
            float h[8]; float ssq = 0.f;
            #pragma unroll
            for (int nt = 0; nt < 8; ++nt) {
                const int col = nt * 16 + l15;
                float v1 = acc1[mt][nt][r] + b[col];
                float v2 = acc2[mt][nt][r] + bagg[col];
                if (!LAST) {
                    v1 = v1 > 0.f ? v1 : 0.1f * v1;
                    v2 = v2 > 0.f ? v2 : 0.1f * v2;
                }
                h[nt] = v1 + v2;
                ssq += h[nt] * h[nt];
            }
            if (LAST) {
                float* orow = outF + (size_t)grow * 128;
                #pragma unroll
                for (int nt = 0; nt < 8; ++nt) orow[nt * 16 + l15] = h[nt];
            } else {
                // a row's 128 cols live on 16 lanes (same quad) x 8 n-tiles
                ssq += __shfl_xor(ssq, 1);
                ssq += __shfl_xor(ssq, 2);
                ssq += __shfl_xor(ssq, 4);
                ssq += __shfl_xor(ssq, 8);
                const float scale = 1.f / fmaxf(sqrtf(ssq), 1e-6f);
                unsigned short* orow = outB + (size_t)grow * 128;
                #pragma unroll
                for (int nt = 0; nt < 8; ++nt) orow[nt * 16 + l15] = f2b(h[nt] * scale);
            }
        }
    }
}

extern "C" void kernel_launch(void* const* d_in, const int* in_sizes, int n_in,
                              void* d_out, int out_size, void* d_ws, size_t ws_size,
                              hipStream_t stream)
{
    const float* node_emb = (const float*)d_in[0];
    const float* content0 = (const float*)d_in[1];
    const float* Wp    = (const float*)d_in[2];
    const float* bp    = (const float*)d_in[3];
    const float* W0    = (const float*)d_in[4];
    const float* b0    = (const float*)d_in[5];
    const float* Wagg0 = (const float*)d_in[6];
    const float* bagg0 = (const float*)d_in[7];
    const float* W1    = (const float*)d_in[8];
    const float* b1    = (const float*)d_in[9];
    const float* Wagg1 = (const float*)d_in[10];
    const float* bagg1 = (const float*)d_in[11];
    const int* parent0 = (const int*)d_in[12];
    const int* src0    = (const int*)d_in[13];
    const int* src1    = (const int*)d_in[15];

    // workspace: h0 (bf16, 170MB) | h1 (19MB) | hagg0 (19MB) | hagg1 (2MB) = 200MiB
    unsigned short* h0    = (unsigned short*)d_ws;
    unsigned short* h1    = h0 + (size_t)S0N * 128;
    unsigned short* hagg0 = h1 + (size_t)S1N * 128;
    unsigned short* hagg1 = hagg0 + (size_t)S1N * 128;

    // 1) h0 = node_emb[parent+1] + leaky(content @ Wp^T + bp)
    k_h0<<<S0N / 128, 256, 0, stream>>>(content0, Wp, bp, node_emb, parent0, h0);
    // 2) hagg0[d] = mean of 8 sampled h0 rows (self-edge cancels h_dst exactly, w=9)
    k_gather<<<S1N / 4, 256, 0, stream>>>(h0, src0, S1N, nullptr, nullptr, hagg0);
    // 3) h1 = normalize(leaky(...) + leaky(...))
    k_combine<false><<<S1N / 128, 256, 0, stream>>>(h0, hagg0, W0, b0, Wagg0, bagg0, h1, nullptr);
    // 4) hagg1[d] = (h1[d] + sum8 h1[s] - h0[d]) / 8   (h_dst = h0[:S2] here!)
    k_gather<<<S2N / 4, 256, 0, stream>>>(h1, src1, S2N, h1, h0, hagg1);
    // 5) out = (concat @ W1^T + b1) + (hagg1 @ Wagg1^T + bagg1), fp32
    k_combine<true><<<S2N / 128, 256, 0, stream>>>(h0, hagg1, W1, b1, Wagg1, bagg1, nullptr, (float*)d_out);
}